// Round 2
// baseline (3156.028 us; speedup 1.0000x reference)
//
#include <hip/hip_runtime.h>
#include <math.h>

#define NTRAJ 32
#define TLEN  64
#define BATCH (NTRAJ*TLEN)   // 2048

__device__ __forceinline__ float eluf(float x){ return x > 0.f ? x : expm1f(x); }
__device__ __forceinline__ float sigmf(float x){ return 1.f/(1.f+expf(-x)); }

// ---------------- conv1: NHWC (C=4) input -> 32 channel planes ----------------
// 4 output pixels per thread (streams 256 apart -> coalesced); weights in LDS.
__global__ __launch_bounds__(256) void conv1_kernel(
    const float* __restrict__ in,   // [2048][84][84][4]
    const float* __restrict__ w,    // [3][3][4][32] HWIO (1152 floats)
    const float* __restrict__ b,    // [32]
    float* __restrict__ out)        // [32][2048*42*42]
{
    __shared__ float ws[1152];
    for(int i=threadIdx.x; i<1152; i+=256) ws[i] = w[i];
    __syncthreads();
    const int NPOS = BATCH*42*42;
    int base = blockIdx.x*1024;
    int n[4], iy0[4], ix0[4];
    float acc[4][32];
    #pragma unroll
    for(int p=0;p<4;p++){
        int pos = base + p*256 + threadIdx.x;
        int nn  = pos / (42*42);
        int rem = pos % (42*42);
        n[p] = nn; iy0[p] = 2*(rem/42); ix0[p] = 2*(rem%42);
        #pragma unroll
        for(int o=0;o<32;o++) acc[p][o] = b[o];
    }
    for(int ky=0; ky<3; ky++){
        for(int kx=0; kx<3; kx++){
            float x[4][4];
            #pragma unroll
            for(int p=0;p<4;p++){
                int iy = iy0[p]+ky, ix = ix0[p]+kx;
                bool ok = (iy<84) & (ix<84);
                int iyc = iy<84?iy:83, ixc = ix<84?ix:83;
                float4 v = *(const float4*)(in + (((n[p]*84 + iyc)*84) + ixc)*4);
                x[p][0] = ok ? v.x : 0.f; x[p][1] = ok ? v.y : 0.f;
                x[p][2] = ok ? v.z : 0.f; x[p][3] = ok ? v.w : 0.f;
            }
            const float* wt = ws + (ky*3+kx)*128;
            #pragma unroll
            for(int q=0;q<4;q++){
                #pragma unroll
                for(int o4=0;o4<8;o4++){
                    float4 w4 = *(const float4*)(wt + q*32 + o4*4);
                    #pragma unroll
                    for(int p=0;p<4;p++){
                        acc[p][o4*4+0] += x[p][q]*w4.x;
                        acc[p][o4*4+1] += x[p][q]*w4.y;
                        acc[p][o4*4+2] += x[p][q]*w4.z;
                        acc[p][o4*4+3] += x[p][q]*w4.w;
                    }
                }
            }
        }
    }
    #pragma unroll
    for(int p=0;p<4;p++){
        int pos = base + p*256 + threadIdx.x;
        #pragma unroll
        for(int o=0;o<32;o++) out[o*NPOS + pos] = eluf(acc[p][o]);
    }
}

// ---------------- conv2/3/4: 32 planes -> 32 planes, PX pixels/thread --------
template<int IH, int IW, int OH, int OW, int PB, int PX>
__global__ __launch_bounds__(256) void convN_kernel(
    const float* __restrict__ in,   // [32][BATCH*IH*IW]
    const float* __restrict__ w,    // [3][3][32][32] HWIO
    const float* __restrict__ b,    // [32]
    float* __restrict__ out)        // [32][BATCH*OH*OW]
{
    const int IPLANE = BATCH*IH*IW;
    const int OPLANE = BATCH*OH*OW;
    __shared__ float ws[9216];
    for(int i=threadIdx.x; i<9216; i+=256) ws[i] = w[i];
    __syncthreads();
    int base = blockIdx.x*(256*PX);
    int n[PX], iy0[PX], ix0[PX];
    float acc[PX][32];
    #pragma unroll
    for(int p=0;p<PX;p++){
        int pos = base + p*256 + threadIdx.x;
        int nn  = pos / (OH*OW);
        int rem = pos % (OH*OW);
        n[p] = nn; iy0[p] = 2*(rem/OW) - PB; ix0[p] = 2*(rem%OW) - PB;
        #pragma unroll
        for(int o=0;o<32;o++) acc[p][o] = b[o];
    }
    for(int ky=0; ky<3; ky++){
        for(int kx=0; kx<3; kx++){
            const float* wt = ws + (ky*3+kx)*1024;
            const float* ipb[PX]; bool okm[PX];
            #pragma unroll
            for(int p=0;p<PX;p++){
                int iy = iy0[p]+ky, ix = ix0[p]+kx;
                okm[p] = (iy>=0) & (iy<IH) & (ix>=0) & (ix<IW);
                int iyc = iy<0?0:(iy>=IH?IH-1:iy);
                int ixc = ix<0?0:(ix>=IW?IW-1:ix);
                ipb[p] = in + (n[p]*IH + iyc)*IW + ixc;
            }
            for(int ci=0; ci<32; ci+=4){
                float x[PX][4];
                #pragma unroll
                for(int p=0;p<PX;p++){
                    #pragma unroll
                    for(int q=0;q<4;q++){
                        float v = ipb[p][(ci+q)*IPLANE];
                        x[p][q] = okm[p] ? v : 0.f;
                    }
                }
                #pragma unroll
                for(int q=0;q<4;q++){
                    #pragma unroll
                    for(int o4=0;o4<8;o4++){
                        float4 w4 = *(const float4*)(wt + (ci+q)*32 + o4*4);
                        #pragma unroll
                        for(int p=0;p<PX;p++){
                            acc[p][o4*4+0] += x[p][q]*w4.x;
                            acc[p][o4*4+1] += x[p][q]*w4.y;
                            acc[p][o4*4+2] += x[p][q]*w4.z;
                            acc[p][o4*4+3] += x[p][q]*w4.w;
                        }
                    }
                }
            }
        }
    }
    #pragma unroll
    for(int p=0;p<PX;p++){
        int pos = base + p*256 + threadIdx.x;
        #pragma unroll
        for(int o=0;o<32;o++) out[o*OPLANE + pos] = eluf(acc[p][o]);
    }
}

// ---------------- conv4 planes -> A_T[feat=1152][row=2048], row = t*32+n ------
__global__ __launch_bounds__(256) void relayout_kernel(
    const float* __restrict__ p4,   // [32][2048*36]
    float* __restrict__ at)         // [1152][2048]
{
    int i = blockIdx.x*256 + threadIdx.x;   // 2,359,296 exactly
    int f = i >> 11, r = i & 2047;          // write coalesced over r
    int s = f >> 5,  c = f & 31;            // feat = (y*6+x)*32 + c
    int t = r >> 5,  n = r & 31;            // r = t*32 + n
    int nt = n*64 + t;
    at[i] = p4[c*(BATCH*36) + nt*36 + s];
}

// ---------------- gate pre-projection: gx[r][1024] = A_T^T @ Wx + b ----------
__global__ __launch_bounds__(256) void gx_gemm_kernel(
    const float* __restrict__ at,   // [1152][2048]
    const float* __restrict__ lw,   // [1408][1024] (rows 0..1151 = Wx)
    const float* __restrict__ lb,   // [1024]
    float* __restrict__ gx)         // [2048][1024], row r = t*32+n
{
    int lane = threadIdx.x & 63;
    int wv   = threadIdx.x >> 6;
    int r0   = blockIdx.x * 16;                    // grid.x = 128
    int oc   = blockIdx.y*256 + wv*64 + lane;      // grid.y = 4
    float acc[16];
    float bias = lb[oc];
    #pragma unroll
    for(int i=0;i<16;i++) acc[i] = bias;
    #pragma unroll 4
    for(int k=0;k<1152;k++){
        float wval = lw[k*1024 + oc];              // coalesced v-load
        const float* ap = at + k*2048 + r0;        // uniform -> s_load
        #pragma unroll
        for(int i=0;i<16;i++) acc[i] += ap[i] * wval;
    }
    #pragma unroll
    for(int i=0;i<16;i++) gx[(r0+i)*1024 + oc] = acc[i];  // coalesced
}

// ---------------- sequential LSTM: 32 WGs, Wh register-resident --------------
// thread t holds Wh[:,t] in 256 VGPRs; per step: 64 ds_read_b128 of h + 256 FMA.
__global__ __launch_bounds__(1024) void lstm_kernel(
    const float* __restrict__ gx,   // [2048][1024], row = t*32+n (bias folded)
    const float* __restrict__ lw,   // [1408][1024]
    const float* __restrict__ c0,   // [32][256]
    const float* __restrict__ h0,   // [32][256]
    float* __restrict__ feats)      // [2048][256], row = n*64+t
{
    __shared__ float hs[256];
    __shared__ float gb[1024];
    const int t = threadIdx.x;      // gate column 0..1023
    const int n = blockIdx.x;       // trajectory
    const float* wh = lw + 1152*1024;
    float w[256];                   // Wh[:,t] resident in VGPRs
    #pragma unroll
    for(int k=0;k<256;k++) w[k] = wh[k*1024 + t];
    if(t < 256) hs[t] = h0[n*256 + t];
    float c = (t < 256) ? c0[n*256 + t] : 0.f;
    __syncthreads();
    for(int st=0; st<64; st++){
        float g = gx[(st*32 + n)*1024 + t];       // prefetch, latency hidden
        float a0=0.f, a1=0.f, a2=0.f, a3=0.f;
        #pragma unroll
        for(int k4=0;k4<64;k4++){
            float4 h4 = *(const float4*)&hs[k4*4];  // LDS broadcast
            a0 += h4.x*w[4*k4+0];
            a1 += h4.y*w[4*k4+1];
            a2 += h4.z*w[4*k4+2];
            a3 += h4.w*w[4*k4+3];
        }
        gb[t] = (a0+a1)+(a2+a3) + g;
        __syncthreads();
        if(t < 256){
            float i_ = gb[t], j_ = gb[t+256], f_ = gb[t+512], o_ = gb[t+768];
            c = c*sigmf(f_+1.f) + sigmf(i_)*tanhf(j_);
            float h = tanhf(c)*sigmf(o_);
            hs[t] = h;
            feats[(n*64 + st)*256 + t] = h;
        }
        __syncthreads();
    }
}

// ---------------- final FC: logits[p][18] = feats[p] @ fc_w + fc_b ----------
__global__ __launch_bounds__(64) void fc_kernel(
    const float* __restrict__ feats, const float* __restrict__ fw,
    const float* __restrict__ fb,    float* __restrict__ out)
{
    __shared__ float h[256];
    int p = blockIdx.x, t = threadIdx.x;
    *(float4*)&h[t*4] = *(const float4*)(feats + p*256 + t*4);
    __syncthreads();
    if(t < 18){
        float acc = fb[t];
        for(int k=0;k<256;k++) acc += h[k]*fw[k*18 + t];
        out[p*18 + t] = acc;
    }
}

extern "C" void kernel_launch(void* const* d_in, const int* in_sizes, int n_in,
                              void* d_out, int out_size, void* d_ws, size_t ws_size,
                              hipStream_t stream) {
    const float* inp = (const float*)d_in[0];
    const float* w1  = (const float*)d_in[1];  const float* b1 = (const float*)d_in[2];
    const float* w2  = (const float*)d_in[3];  const float* b2 = (const float*)d_in[4];
    const float* w3  = (const float*)d_in[5];  const float* b3 = (const float*)d_in[6];
    const float* w4  = (const float*)d_in[7];  const float* b4 = (const float*)d_in[8];
    const float* lw  = (const float*)d_in[9];  const float* lb = (const float*)d_in[10];
    const float* fw  = (const float*)d_in[11]; const float* fb = (const float*)d_in[12];
    const float* c0  = (const float*)d_in[13]; const float* h0 = (const float*)d_in[14];
    float* out = (float*)d_out;
    float* ws  = (float*)d_ws;

    const size_t n1 = (size_t)32*3612672;   // conv1 out planes
    const size_t n3 = (size_t)32*247808;    // conv3 out planes
    const size_t n4 = (size_t)32*73728;     // conv4 out planes

    float* p1 = ws;
    float* p2 = p1 + n1;                    // conv2 out
    float* p3 = ws;                         // reuse p1 region (conv3 reads only p2)
    float* p4 = p3 + n3;
    float* at = p4 + n4;                    // [1152][2048]
    float* gxb   = at  + (size_t)1152*2048; // [2048][1024]
    float* feats = gxb + (size_t)2048*1024; // [2048][256]

    conv1_kernel<<<3528,256,0,stream>>>(inp, w1, b1, p1);
    convN_kernel<42,42,21,21,0,4><<<882,256,0,stream>>>(p1, w2, b2, p2);
    convN_kernel<21,21,11,11,1,4><<<242,256,0,stream>>>(p2, w3, b3, p3);
    convN_kernel<11,11, 6, 6,1,1><<<288,256,0,stream>>>(p3, w4, b4, p4);
    relayout_kernel<<<9216,256,0,stream>>>(p4, at);
    gx_gemm_kernel<<<dim3(128,4),256,0,stream>>>(at, lw, lb, gxb);
    lstm_kernel<<<32,1024,0,stream>>>(gxb, lw, c0, h0, feats);
    fc_kernel<<<2048,64,0,stream>>>(feats, fw, fb, out);
}

// Round 3
// 2522.801 us; speedup vs baseline: 1.2510x; 1.2510x over previous
//
#include <hip/hip_runtime.h>
#include <hip/hip_cooperative_groups.h>
#include <math.h>

namespace cg = cooperative_groups;

#define NTRAJ 32
#define TLEN  64
#define BATCH (NTRAJ*TLEN)   // 2048

__device__ __forceinline__ float eluf(float x){ return x > 0.f ? x : expm1f(x); }
__device__ __forceinline__ float sigmf(float x){ return 1.f/(1.f+expf(-x)); }

// ---------------- conv1: NHWC (C=4) input -> 32 channel planes (R1 version) --
__global__ __launch_bounds__(256) void conv1_kernel(
    const float* __restrict__ in,   // [2048][84][84][4]
    const float* __restrict__ w,    // [3][3][4][32] HWIO
    const float* __restrict__ b,    // [32]
    float* __restrict__ out)        // [32][2048*42*42]
{
    int pos = blockIdx.x*256 + threadIdx.x;
    int n   = pos / (42*42);
    int rem = pos % (42*42);
    int oy  = rem / 42, ox = rem % 42;
    float acc[32];
    #pragma unroll
    for(int o=0;o<32;o++) acc[o] = b[o];
    for(int ky=0; ky<3; ky++){
        int iy = 2*oy + ky;
        if(iy >= 84) continue;
        for(int kx=0; kx<3; kx++){
            int ix = 2*ox + kx;
            if(ix >= 84) continue;
            float4 v = *(const float4*)(in + (((n*84 + iy)*84) + ix)*4);
            const float* wq = w + (ky*3 + kx)*128;
            #pragma unroll
            for(int o=0;o<32;o++) acc[o] += v.x*wq[o];
            #pragma unroll
            for(int o=0;o<32;o++) acc[o] += v.y*wq[32+o];
            #pragma unroll
            for(int o=0;o<32;o++) acc[o] += v.z*wq[64+o];
            #pragma unroll
            for(int o=0;o<32;o++) acc[o] += v.w*wq[96+o];
        }
    }
    const int NPOS = BATCH*42*42;
    #pragma unroll
    for(int o=0;o<32;o++) out[o*NPOS + pos] = eluf(acc[o]);
}

// ---------------- conv2/3/4: 32 planes -> 32 planes (R1 version) -------------
template<int IH, int IW, int OH, int OW, int PB>
__global__ __launch_bounds__(256) void convN_kernel(
    const float* __restrict__ in,   // [32][BATCH*IH*IW]
    const float* __restrict__ w,    // [3][3][32][32] HWIO
    const float* __restrict__ b,    // [32]
    float* __restrict__ out)        // [32][BATCH*OH*OW]
{
    const int IPLANE = BATCH*IH*IW;
    const int OPLANE = BATCH*OH*OW;
    int pos = blockIdx.x*256 + threadIdx.x;
    if(pos >= OPLANE) return;
    int n   = pos / (OH*OW);
    int rem = pos % (OH*OW);
    int oy  = rem / OW, ox = rem % OW;
    float acc[32];
    #pragma unroll
    for(int o=0;o<32;o++) acc[o] = b[o];
    for(int ky=0; ky<3; ky++){
        int iy = 2*oy + ky - PB;
        if(iy < 0 || iy >= IH) continue;
        for(int kx=0; kx<3; kx++){
            int ix = 2*ox + kx - PB;
            if(ix < 0 || ix >= IW) continue;
            const float* ip = in + (n*IH + iy)*IW + ix;
            const float* wp = w + (ky*3 + kx)*1024;
            for(int ci=0; ci<32; ci+=4){
                float x0 = ip[(ci+0)*IPLANE];
                float x1 = ip[(ci+1)*IPLANE];
                float x2 = ip[(ci+2)*IPLANE];
                float x3 = ip[(ci+3)*IPLANE];
                const float* wq = wp + ci*32;
                #pragma unroll
                for(int o=0;o<32;o++) acc[o] += x0*wq[o];
                #pragma unroll
                for(int o=0;o<32;o++) acc[o] += x1*wq[32+o];
                #pragma unroll
                for(int o=0;o<32;o++) acc[o] += x2*wq[64+o];
                #pragma unroll
                for(int o=0;o<32;o++) acc[o] += x3*wq[96+o];
            }
        }
    }
    #pragma unroll
    for(int o=0;o<32;o++) out[o*OPLANE + pos] = eluf(acc[o]);
}

// ---------------- conv4 planes -> A_T[feat=1152][row=2048], row = t*32+n ------
__global__ __launch_bounds__(256) void relayout_kernel(
    const float* __restrict__ p4,   // [32][2048*36]
    float* __restrict__ at)         // [1152][2048]
{
    int i = blockIdx.x*256 + threadIdx.x;
    int f = i >> 11, r = i & 2047;
    int s = f >> 5,  c = f & 31;
    int t = r >> 5,  n = r & 31;
    int nt = n*64 + t;
    at[i] = p4[c*(BATCH*36) + nt*36 + s];
}

// ---------------- gate pre-projection: gx[r][1024] = A_T^T @ Wx + b ----------
__global__ __launch_bounds__(256) void gx_gemm_kernel(
    const float* __restrict__ at,   // [1152][2048]
    const float* __restrict__ lw,   // [1408][1024] (rows 0..1151 = Wx)
    const float* __restrict__ lb,   // [1024]
    float* __restrict__ gx)         // [2048][1024], row r = t*32+n
{
    int lane = threadIdx.x & 63;
    int wv   = threadIdx.x >> 6;
    int r0   = blockIdx.x * 16;
    int oc   = blockIdx.y*256 + wv*64 + lane;
    float acc[16];
    float bias = lb[oc];
    #pragma unroll
    for(int i=0;i<16;i++) acc[i] = bias;
    #pragma unroll 4
    for(int k=0;k<1152;k++){
        float wval = lw[k*1024 + oc];
        const float* ap = at + k*2048 + r0;
        #pragma unroll
        for(int i=0;i<16;i++) acc[i] += ap[i] * wval;
    }
    #pragma unroll
    for(int i=0;i<16;i++) gx[(r0+i)*1024 + oc] = acc[i];
}

// ---------------- cooperative LSTM: 32 WGs, Wh VGPR-resident slices ----------
// WG wg owns 8 hidden units (32 gate cols). Thread t: cols {t&15, (t&15)+16},
// ksegs rows [ (t>>4)*16, +16 ) -> 32 weight VGPRs. h exchanged via hbuf +
// grid.sync each step. No Wh memory traffic after preload.
__global__ __launch_bounds__(256) void lstm_kernel(
    const float* __restrict__ gx,   // [2048][1024], row = st*32+n (bias folded)
    const float* __restrict__ lw,   // [1408][1024]
    const float* __restrict__ c0,   // [32][256]
    const float* __restrict__ h0,   // [32][256]
    float* __restrict__ feats,      // [2048][256], row = n*64+st
    float* __restrict__ hbuf)       // [2][32][256] double buffer
{
    cg::grid_group grid = cg::this_grid();
    __shared__ float h_s[8192];          // [32][256] current h, all trajs
    __shared__ float part[4][32][33];    // per-wave partial sums (+1 pad)
    __shared__ float gatef[32][32];      // [col32][n] final gates
    const int t    = threadIdx.x;
    const int wg   = blockIdx.x;         // 0..31
    const int col16= t & 15;
    const int kseg = t >> 4;             // 0..15
    const int lane = t & 63;
    const int wv   = t >> 6;             // wave 0..3
    const float* wh = lw + 1152*1024;

    // colX in [0,32): global col = (colX>>3)*256 + wg*8 + (colX&7)
    const int gAc = ((col16>>3)<<8)      + wg*8 + (col16&7);        // colX=col16
    const int gBc = (((col16+16)>>3)<<8) + wg*8 + ((col16+16)&7);   // colX=col16+16

    float wAr[16], wBr[16];
    #pragma unroll
    for(int j=0;j<16;j++){
        wAr[j] = wh[(kseg*16+j)*1024 + gAc];
        wBr[j] = wh[(kseg*16+j)*1024 + gBc];
    }
    // c-state ownership: thread t -> (n = t&31, unit ui = t>>5)
    const int cn = t & 31, cu = t >> 5;
    const int uglob = wg*8 + cu;
    float c = c0[cn*256 + uglob];
    hbuf[wg*256 + t] = h0[wg*256 + t];   // 32*256 = 8192 covered exactly
    __threadfence();
    grid.sync();

    for(int st=0; st<64; st++){
        // stage current h into LDS (coalesced)
        const float* hsrc = hbuf + (st&1)*8192;
        #pragma unroll
        for(int r=0;r<8;r++){
            int off = r*1024 + t*4;
            *(float4*)&h_s[off] = *(const float4*)&hsrc[off];
        }
        __syncthreads();
        // dot phase: partial gates for all 32 trajs
        #pragma unroll 4
        for(int n=0;n<32;n++){
            const float4* hp = (const float4*)&h_s[n*256 + kseg*16];
            float4 ha = hp[0], hb = hp[1], hc = hp[2], hd = hp[3];
            float pA = ha.x*wAr[0]  + ha.y*wAr[1]  + ha.z*wAr[2]  + ha.w*wAr[3]
                     + hb.x*wAr[4]  + hb.y*wAr[5]  + hb.z*wAr[6]  + hb.w*wAr[7]
                     + hc.x*wAr[8]  + hc.y*wAr[9]  + hc.z*wAr[10] + hc.w*wAr[11]
                     + hd.x*wAr[12] + hd.y*wAr[13] + hd.z*wAr[14] + hd.w*wAr[15];
            float pB = ha.x*wBr[0]  + ha.y*wBr[1]  + ha.z*wBr[2]  + ha.w*wBr[3]
                     + hb.x*wBr[4]  + hb.y*wBr[5]  + hb.z*wBr[6]  + hb.w*wBr[7]
                     + hc.x*wBr[8]  + hc.y*wBr[9]  + hc.z*wBr[10] + hc.w*wBr[11]
                     + hd.x*wBr[12] + hd.y*wBr[13] + hd.z*wBr[14] + hd.w*wBr[15];
            pA += __shfl_xor(pA, 16, 64);
            pA += __shfl_xor(pA, 32, 64);
            pB += __shfl_xor(pB, 16, 64);
            pB += __shfl_xor(pB, 32, 64);
            if(lane < 16){
                part[wv][n][lane]    = pA;
                part[wv][n][lane+16] = pB;
            }
        }
        __syncthreads();
        // assembly: 1024 gate values = 4 per thread
        #pragma unroll
        for(int e=0;e<4;e++){
            int idx  = t + e*256;
            int n    = idx & 31, colX = idx >> 5;
            int cg_  = ((colX>>3)<<8) + wg*8 + (colX&7);
            float s  = part[0][n][colX] + part[1][n][colX]
                     + part[2][n][colX] + part[3][n][colX];
            gatef[colX][n] = s + gx[(st*32 + n)*1024 + cg_];
        }
        __syncthreads();
        // update: thread owns (cn, cu)
        float i_ = gatef[cu][cn],    j_ = gatef[8+cu][cn],
              f_ = gatef[16+cu][cn], o_ = gatef[24+cu][cn];
        c = c*sigmf(f_+1.f) + sigmf(i_)*tanhf(j_);
        float h = tanhf(c)*sigmf(o_);
        hbuf[((st+1)&1)*8192 + cn*256 + uglob] = h;
        feats[(cn*64 + st)*256 + uglob] = h;
        __threadfence();
        grid.sync();
    }
}

// ---------------- final FC: logits[p][18] = feats[p] @ fc_w + fc_b ----------
__global__ __launch_bounds__(64) void fc_kernel(
    const float* __restrict__ feats, const float* __restrict__ fw,
    const float* __restrict__ fb,    float* __restrict__ out)
{
    __shared__ float h[256];
    int p = blockIdx.x, t = threadIdx.x;
    *(float4*)&h[t*4] = *(const float4*)(feats + p*256 + t*4);
    __syncthreads();
    if(t < 18){
        float acc = fb[t];
        for(int k=0;k<256;k++) acc += h[k]*fw[k*18 + t];
        out[p*18 + t] = acc;
    }
}

extern "C" void kernel_launch(void* const* d_in, const int* in_sizes, int n_in,
                              void* d_out, int out_size, void* d_ws, size_t ws_size,
                              hipStream_t stream) {
    const float* inp = (const float*)d_in[0];
    const float* w1  = (const float*)d_in[1];  const float* b1 = (const float*)d_in[2];
    const float* w2  = (const float*)d_in[3];  const float* b2 = (const float*)d_in[4];
    const float* w3  = (const float*)d_in[5];  const float* b3 = (const float*)d_in[6];
    const float* w4  = (const float*)d_in[7];  const float* b4 = (const float*)d_in[8];
    const float* lw  = (const float*)d_in[9];  const float* lb = (const float*)d_in[10];
    const float* fw  = (const float*)d_in[11]; const float* fb = (const float*)d_in[12];
    const float* c0  = (const float*)d_in[13]; const float* h0 = (const float*)d_in[14];
    float* out = (float*)d_out;
    float* ws  = (float*)d_ws;

    const size_t n1 = (size_t)32*3612672;   // conv1 out planes
    const size_t n3 = (size_t)32*247808;    // conv3 out planes
    const size_t n4 = (size_t)32*73728;     // conv4 out planes

    float* p1 = ws;
    float* p2 = p1 + n1;                    // conv2 out
    float* p3 = ws;                         // reuse p1 region (conv3 reads only p2)
    float* p4 = p3 + n3;
    float* at = p4 + n4;                    // [1152][2048]
    float* gxb   = at  + (size_t)1152*2048; // [2048][1024]
    float* feats = gxb + (size_t)2048*1024; // [2048][256]
    float* hbuf  = feats + (size_t)2048*256;// [2][32][256]

    conv1_kernel<<<14112,256,0,stream>>>(inp, w1, b1, p1);
    convN_kernel<42,42,21,21,0><<<3528,256,0,stream>>>(p1, w2, b2, p2);
    convN_kernel<21,21,11,11,1><<<968,256,0,stream>>>(p2, w3, b3, p3);
    convN_kernel<11,11, 6, 6,1><<<288,256,0,stream>>>(p3, w4, b4, p4);
    relayout_kernel<<<9216,256,0,stream>>>(p4, at);
    gx_gemm_kernel<<<dim3(128,4),256,0,stream>>>(at, lw, lb, gxb);
    {
        void* args[] = { (void*)&gxb, (void*)&lw, (void*)&c0, (void*)&h0,
                         (void*)&feats, (void*)&hbuf };
        hipLaunchCooperativeKernel((void*)lstm_kernel, dim3(32), dim3(256),
                                   args, 0, stream);
    }
    fc_kernel<<<2048,64,0,stream>>>(feats, fw, fb, out);
}

// Round 4
// 2440.387 us; speedup vs baseline: 1.2932x; 1.0338x over previous
//
#include <hip/hip_runtime.h>
#include <math.h>

#define NTRAJ 32
#define TLEN  64
#define BATCH (NTRAJ*TLEN)   // 2048

__device__ __forceinline__ float eluf(float x){ return x > 0.f ? x : expm1f(x); }
__device__ __forceinline__ float sigmf(float x){ return 1.f/(1.f+expf(-x)); }

// ---------------- conv1: NHWC (C=4) input -> 32 channel planes ----------------
__global__ __launch_bounds__(256) void conv1_kernel(
    const float* __restrict__ in,   // [2048][84][84][4]
    const float* __restrict__ w,    // [3][3][4][32] HWIO
    const float* __restrict__ b,    // [32]
    float* __restrict__ out)        // [32][2048*42*42]
{
    int pos = blockIdx.x*256 + threadIdx.x;
    int n   = pos / (42*42);
    int rem = pos % (42*42);
    int oy  = rem / 42, ox = rem % 42;
    float acc[32];
    #pragma unroll
    for(int o=0;o<32;o++) acc[o] = b[o];
    for(int ky=0; ky<3; ky++){
        int iy = 2*oy + ky;
        if(iy >= 84) continue;
        for(int kx=0; kx<3; kx++){
            int ix = 2*ox + kx;
            if(ix >= 84) continue;
            float4 v = *(const float4*)(in + (((n*84 + iy)*84) + ix)*4);
            const float* wq = w + (ky*3 + kx)*128;
            #pragma unroll
            for(int o=0;o<32;o++) acc[o] += v.x*wq[o];
            #pragma unroll
            for(int o=0;o<32;o++) acc[o] += v.y*wq[32+o];
            #pragma unroll
            for(int o=0;o<32;o++) acc[o] += v.z*wq[64+o];
            #pragma unroll
            for(int o=0;o<32;o++) acc[o] += v.w*wq[96+o];
        }
    }
    const int NPOS = BATCH*42*42;
    #pragma unroll
    for(int o=0;o<32;o++) out[o*NPOS + pos] = eluf(acc[o]);
}

// ---------------- conv2/3/4: 32 planes -> 32 planes --------------------------
template<int IH, int IW, int OH, int OW, int PB>
__global__ __launch_bounds__(256) void convN_kernel(
    const float* __restrict__ in,   // [32][BATCH*IH*IW]
    const float* __restrict__ w,    // [3][3][32][32] HWIO
    const float* __restrict__ b,    // [32]
    float* __restrict__ out)        // [32][BATCH*OH*OW]
{
    const int IPLANE = BATCH*IH*IW;
    const int OPLANE = BATCH*OH*OW;
    int pos = blockIdx.x*256 + threadIdx.x;
    if(pos >= OPLANE) return;
    int n   = pos / (OH*OW);
    int rem = pos % (OH*OW);
    int oy  = rem / OW, ox = rem % OW;
    float acc[32];
    #pragma unroll
    for(int o=0;o<32;o++) acc[o] = b[o];
    for(int ky=0; ky<3; ky++){
        int iy = 2*oy + ky - PB;
        if(iy < 0 || iy >= IH) continue;
        for(int kx=0; kx<3; kx++){
            int ix = 2*ox + kx - PB;
            if(ix < 0 || ix >= IW) continue;
            const float* ip = in + (n*IH + iy)*IW + ix;
            const float* wp = w + (ky*3 + kx)*1024;
            #pragma unroll
            for(int ci=0; ci<32; ci+=4){
                float x0 = ip[(ci+0)*IPLANE];
                float x1 = ip[(ci+1)*IPLANE];
                float x2 = ip[(ci+2)*IPLANE];
                float x3 = ip[(ci+3)*IPLANE];
                const float* wq = wp + ci*32;
                #pragma unroll
                for(int o=0;o<32;o++) acc[o] += x0*wq[o];
                #pragma unroll
                for(int o=0;o<32;o++) acc[o] += x1*wq[32+o];
                #pragma unroll
                for(int o=0;o<32;o++) acc[o] += x2*wq[64+o];
                #pragma unroll
                for(int o=0;o<32;o++) acc[o] += x3*wq[96+o];
            }
        }
    }
    #pragma unroll
    for(int o=0;o<32;o++) out[o*OPLANE + pos] = eluf(acc[o]);
}

// ---------------- conv4 planes -> A_T[feat=1152][row=2048], row = t*32+n ------
__global__ __launch_bounds__(256) void relayout_kernel(
    const float* __restrict__ p4,   // [32][2048*36]
    float* __restrict__ at)         // [1152][2048]
{
    int i = blockIdx.x*256 + threadIdx.x;
    int f = i >> 11, r = i & 2047;
    int s = f >> 5,  c = f & 31;
    int t = r >> 5,  n = r & 31;
    int nt = n*64 + t;
    at[i] = p4[c*(BATCH*36) + nt*36 + s];
}

// ---------------- gate pre-projection: gx[r][1024] = A_T^T @ Wx + b ----------
__global__ __launch_bounds__(256) void gx_gemm_kernel(
    const float* __restrict__ at,   // [1152][2048]
    const float* __restrict__ lw,   // [1408][1024] (rows 0..1151 = Wx)
    const float* __restrict__ lb,   // [1024]
    float* __restrict__ gx)         // [2048][1024], row r = t*32+n
{
    int lane = threadIdx.x & 63;
    int wv   = threadIdx.x >> 6;
    int r0   = blockIdx.x * 16;
    int oc   = blockIdx.y*256 + wv*64 + lane;
    float acc[16];
    float bias = lb[oc];
    #pragma unroll
    for(int i=0;i<16;i++) acc[i] = bias;
    #pragma unroll 4
    for(int k=0;k<1152;k++){
        float wval = lw[k*1024 + oc];
        const float* ap = at + k*2048 + r0;
        #pragma unroll
        for(int i=0;i<16;i++) acc[i] += ap[i] * wval;
    }
    #pragma unroll
    for(int i=0;i<16;i++) gx[(r0+i)*1024 + oc] = acc[i];
}

// ---------------- cooperative LSTM: 32 WGs, custom spin barrier --------------
// WG wg owns 8 hidden units (32 gate cols). Weights VGPR-resident (32/thread).
// h exchanged via AGENT-scope relaxed atomics (bypass non-coherent L1/L2);
// barrier = monotonic counter + release/acquire, no threadfence, no cg.
__global__ __launch_bounds__(256) void lstm_kernel(
    const float* __restrict__ gx,   // [2048][1024], row = st*32+n (bias folded)
    const float* __restrict__ lw,   // [1408][1024]
    const float* __restrict__ c0,   // [32][256]
    const float* __restrict__ h0,   // [32][256]
    float* __restrict__ feats,      // [2048][256], row = n*64+st
    float* __restrict__ hbuf,       // [2][32][256] double buffer
    unsigned* __restrict__ bar)     // zeroed counter
{
    __shared__ float h_s[8192];          // [32][256] current h, all trajs
    __shared__ float part[4][32][33];    // per-wave partial sums (+1 pad)
    __shared__ float gatef[32][32];      // [col32][n] final gates
    const int t    = threadIdx.x;
    const int wg   = blockIdx.x;         // 0..31
    const int col16= t & 15;
    const int kseg = t >> 4;             // 0..15
    const int lane = t & 63;
    const int wv   = t >> 6;             // wave 0..3
    const float* wh = lw + 1152*1024;

    const int gAc = ((col16>>3)<<8)      + wg*8 + (col16&7);
    const int gBc = (((col16+16)>>3)<<8) + wg*8 + ((col16+16)&7);

    float wAr[16], wBr[16];
    #pragma unroll
    for(int j=0;j<16;j++){
        wAr[j] = wh[(kseg*16+j)*1024 + gAc];
        wBr[j] = wh[(kseg*16+j)*1024 + gBc];
    }
    const int cn = t & 31, cu = t >> 5;
    const int uglob = wg*8 + cu;
    float c = c0[cn*256 + uglob];
    // publish h0 slice (agent scope so other XCDs see it)
    {
        float hv = h0[wg*256 + t];
        __hip_atomic_store(&hbuf[wg*256 + t], hv, __ATOMIC_RELAXED,
                           __HIP_MEMORY_SCOPE_AGENT);
    }
    __syncthreads();
    if(t==0){
        __hip_atomic_fetch_add(bar, 1u, __ATOMIC_RELEASE, __HIP_MEMORY_SCOPE_AGENT);
        while(__hip_atomic_load(bar, __ATOMIC_ACQUIRE, __HIP_MEMORY_SCOPE_AGENT) < 32u){}
    }
    __syncthreads();

    for(int st=0; st<64; st++){
        // prefetch this step's gx values (consumed in assembly phase)
        float gpre[4]; int pn[4], pcolX[4];
        #pragma unroll
        for(int e=0;e<4;e++){
            int idx = t + e*256;
            pn[e] = idx & 31; pcolX[e] = idx >> 5;
            int cgc = ((pcolX[e]>>3)<<8) + wg*8 + (pcolX[e]&7);
            gpre[e] = gx[(st*32 + pn[e])*1024 + cgc];
        }
        // stage current h into LDS via agent-scope loads (8B each, coalesced)
        {
            const unsigned long long* hsrc =
                (const unsigned long long*)(hbuf + (st&1)*8192);
            unsigned long long* hdst = (unsigned long long*)h_s;
            #pragma unroll
            for(int r=0;r<16;r++){
                int off = r*256 + t;
                hdst[off] = __hip_atomic_load(&hsrc[off], __ATOMIC_RELAXED,
                                              __HIP_MEMORY_SCOPE_AGENT);
            }
        }
        __syncthreads();
        // dot phase
        #pragma unroll 4
        for(int n=0;n<32;n++){
            const float4* hp = (const float4*)&h_s[n*256 + kseg*16];
            float4 ha = hp[0], hb = hp[1], hc = hp[2], hd = hp[3];
            float pA = ha.x*wAr[0]  + ha.y*wAr[1]  + ha.z*wAr[2]  + ha.w*wAr[3]
                     + hb.x*wAr[4]  + hb.y*wAr[5]  + hb.z*wAr[6]  + hb.w*wAr[7]
                     + hc.x*wAr[8]  + hc.y*wAr[9]  + hc.z*wAr[10] + hc.w*wAr[11]
                     + hd.x*wAr[12] + hd.y*wAr[13] + hd.z*wAr[14] + hd.w*wAr[15];
            float pB = ha.x*wBr[0]  + ha.y*wBr[1]  + ha.z*wBr[2]  + ha.w*wBr[3]
                     + hb.x*wBr[4]  + hb.y*wBr[5]  + hb.z*wBr[6]  + hb.w*wBr[7]
                     + hc.x*wBr[8]  + hc.y*wBr[9]  + hc.z*wBr[10] + hc.w*wBr[11]
                     + hd.x*wBr[12] + hd.y*wBr[13] + hd.z*wBr[14] + hd.w*wBr[15];
            pA += __shfl_xor(pA, 16, 64);
            pA += __shfl_xor(pA, 32, 64);
            pB += __shfl_xor(pB, 16, 64);
            pB += __shfl_xor(pB, 32, 64);
            if(lane < 16){
                part[wv][n][lane]    = pA;
                part[wv][n][lane+16] = pB;
            }
        }
        __syncthreads();
        // assembly: 1024 gate values = 4 per thread
        #pragma unroll
        for(int e=0;e<4;e++){
            float s = part[0][pn[e]][pcolX[e]] + part[1][pn[e]][pcolX[e]]
                    + part[2][pn[e]][pcolX[e]] + part[3][pn[e]][pcolX[e]];
            gatef[pcolX[e]][pn[e]] = s + gpre[e];
        }
        __syncthreads();
        // update: thread owns (cn, cu)
        float i_ = gatef[cu][cn],    j_ = gatef[8+cu][cn],
              f_ = gatef[16+cu][cn], o_ = gatef[24+cu][cn];
        c = c*sigmf(f_+1.f) + sigmf(i_)*tanhf(j_);
        float h = tanhf(c)*sigmf(o_);
        __hip_atomic_store(&hbuf[((st+1)&1)*8192 + cn*256 + uglob], h,
                           __ATOMIC_RELAXED, __HIP_MEMORY_SCOPE_AGENT);
        feats[(cn*64 + st)*256 + uglob] = h;
        if(st < 63){
            __syncthreads();
            if(t==0){
                __hip_atomic_fetch_add(bar, 1u, __ATOMIC_RELEASE,
                                       __HIP_MEMORY_SCOPE_AGENT);
                unsigned tgt = 32u*(unsigned)(st+2);
                while(__hip_atomic_load(bar, __ATOMIC_ACQUIRE,
                                        __HIP_MEMORY_SCOPE_AGENT) < tgt){}
            }
            __syncthreads();
        }
    }
}

// ---------------- final FC: logits[p][18] = feats[p] @ fc_w + fc_b ----------
__global__ __launch_bounds__(64) void fc_kernel(
    const float* __restrict__ feats, const float* __restrict__ fw,
    const float* __restrict__ fb,    float* __restrict__ out)
{
    __shared__ float h[256];
    int p = blockIdx.x, t = threadIdx.x;
    *(float4*)&h[t*4] = *(const float4*)(feats + p*256 + t*4);
    __syncthreads();
    if(t < 18){
        float acc = fb[t];
        for(int k=0;k<256;k++) acc += h[k]*fw[k*18 + t];
        out[p*18 + t] = acc;
    }
}

extern "C" void kernel_launch(void* const* d_in, const int* in_sizes, int n_in,
                              void* d_out, int out_size, void* d_ws, size_t ws_size,
                              hipStream_t stream) {
    const float* inp = (const float*)d_in[0];
    const float* w1  = (const float*)d_in[1];  const float* b1 = (const float*)d_in[2];
    const float* w2  = (const float*)d_in[3];  const float* b2 = (const float*)d_in[4];
    const float* w3  = (const float*)d_in[5];  const float* b3 = (const float*)d_in[6];
    const float* w4  = (const float*)d_in[7];  const float* b4 = (const float*)d_in[8];
    const float* lw  = (const float*)d_in[9];  const float* lb = (const float*)d_in[10];
    const float* fw  = (const float*)d_in[11]; const float* fb = (const float*)d_in[12];
    const float* c0  = (const float*)d_in[13]; const float* h0 = (const float*)d_in[14];
    float* out = (float*)d_out;
    float* ws  = (float*)d_ws;

    const size_t n1 = (size_t)32*3612672;   // conv1 out planes
    const size_t n3 = (size_t)32*247808;    // conv3 out planes
    const size_t n4 = (size_t)32*73728;     // conv4 out planes

    float* p1 = ws;
    float* p2 = p1 + n1;                    // conv2 out
    float* p3 = ws;                         // reuse p1 region (conv3 reads only p2)
    float* p4 = p3 + n3;
    float* at = p4 + n4;                    // [1152][2048]
    float* gxb   = at  + (size_t)1152*2048; // [2048][1024]
    float* feats = gxb + (size_t)2048*1024; // [2048][256]
    float* hbuf  = feats + (size_t)2048*256;// [2][32][256]
    unsigned* bar = (unsigned*)(hbuf + 16384);

    conv1_kernel<<<14112,256,0,stream>>>(inp, w1, b1, p1);
    convN_kernel<42,42,21,21,0><<<3528,256,0,stream>>>(p1, w2, b2, p2);
    convN_kernel<21,21,11,11,1><<<968,256,0,stream>>>(p2, w3, b3, p3);
    convN_kernel<11,11, 6, 6,1><<<288,256,0,stream>>>(p3, w4, b4, p4);
    relayout_kernel<<<9216,256,0,stream>>>(p4, at);
    gx_gemm_kernel<<<dim3(128,4),256,0,stream>>>(at, lw, lb, gxb);
    hipMemsetAsync(bar, 0, 64, stream);
    {
        void* args[] = { (void*)&gxb, (void*)&lw, (void*)&c0, (void*)&h0,
                         (void*)&feats, (void*)&hbuf, (void*)&bar };
        hipLaunchCooperativeKernel((void*)lstm_kernel, dim3(32), dim3(256),
                                   args, 0, stream);
    }
    fc_kernel<<<2048,64,0,stream>>>(feats, fw, fb, out);
}

// Round 5
// 2126.934 us; speedup vs baseline: 1.4838x; 1.1474x over previous
//
#include <hip/hip_runtime.h>
#include <math.h>

#define NTRAJ 32
#define TLEN  64
#define BATCH (NTRAJ*TLEN)   // 2048

__device__ __forceinline__ float eluf(float x){ return x > 0.f ? x : expm1f(x); }
__device__ __forceinline__ float sigmf(float x){ return 1.f/(1.f+expf(-x)); }

// ---------------- conv1: NHWC (C=4) input -> 32 channel planes ----------------
__global__ __launch_bounds__(256) void conv1_kernel(
    const float* __restrict__ in,   // [2048][84][84][4]
    const float* __restrict__ w,    // [3][3][4][32] HWIO
    const float* __restrict__ b,    // [32]
    float* __restrict__ out)        // [32][2048*42*42]
{
    int pos = blockIdx.x*256 + threadIdx.x;
    int n   = pos / (42*42);
    int rem = pos % (42*42);
    int oy  = rem / 42, ox = rem % 42;
    float acc[32];
    #pragma unroll
    for(int o=0;o<32;o++) acc[o] = b[o];
    for(int ky=0; ky<3; ky++){
        int iy = 2*oy + ky;
        if(iy >= 84) continue;
        for(int kx=0; kx<3; kx++){
            int ix = 2*ox + kx;
            if(ix >= 84) continue;
            float4 v = *(const float4*)(in + (((n*84 + iy)*84) + ix)*4);
            const float* wq = w + (ky*3 + kx)*128;
            #pragma unroll
            for(int o=0;o<32;o++) acc[o] += v.x*wq[o];
            #pragma unroll
            for(int o=0;o<32;o++) acc[o] += v.y*wq[32+o];
            #pragma unroll
            for(int o=0;o<32;o++) acc[o] += v.z*wq[64+o];
            #pragma unroll
            for(int o=0;o<32;o++) acc[o] += v.w*wq[96+o];
        }
    }
    const int NPOS = BATCH*42*42;
    #pragma unroll
    for(int o=0;o<32;o++) out[o*NPOS + pos] = eluf(acc[o]);
}

// ---------------- conv2/3/4: 32 planes -> 32 planes --------------------------
template<int IH, int IW, int OH, int OW, int PB>
__global__ __launch_bounds__(256) void convN_kernel(
    const float* __restrict__ in,   // [32][BATCH*IH*IW]
    const float* __restrict__ w,    // [3][3][32][32] HWIO
    const float* __restrict__ b,    // [32]
    float* __restrict__ out)        // [32][BATCH*OH*OW]
{
    const int IPLANE = BATCH*IH*IW;
    const int OPLANE = BATCH*OH*OW;
    int pos = blockIdx.x*256 + threadIdx.x;
    if(pos >= OPLANE) return;
    int n   = pos / (OH*OW);
    int rem = pos % (OH*OW);
    int oy  = rem / OW, ox = rem % OW;
    float acc[32];
    #pragma unroll
    for(int o=0;o<32;o++) acc[o] = b[o];
    for(int ky=0; ky<3; ky++){
        int iy = 2*oy + ky - PB;
        if(iy < 0 || iy >= IH) continue;
        for(int kx=0; kx<3; kx++){
            int ix = 2*ox + kx - PB;
            if(ix < 0 || ix >= IW) continue;
            const float* ip = in + (n*IH + iy)*IW + ix;
            const float* wp = w + (ky*3 + kx)*1024;
            #pragma unroll
            for(int ci=0; ci<32; ci+=4){
                float x0 = ip[(ci+0)*IPLANE];
                float x1 = ip[(ci+1)*IPLANE];
                float x2 = ip[(ci+2)*IPLANE];
                float x3 = ip[(ci+3)*IPLANE];
                const float* wq = wp + ci*32;
                #pragma unroll
                for(int o=0;o<32;o++) acc[o] += x0*wq[o];
                #pragma unroll
                for(int o=0;o<32;o++) acc[o] += x1*wq[32+o];
                #pragma unroll
                for(int o=0;o<32;o++) acc[o] += x2*wq[64+o];
                #pragma unroll
                for(int o=0;o<32;o++) acc[o] += x3*wq[96+o];
            }
        }
    }
    #pragma unroll
    for(int o=0;o<32;o++) out[o*OPLANE + pos] = eluf(acc[o]);
}

// ---------------- conv4 planes -> A_T[feat=1152][row=2048], row = t*32+n ------
__global__ __launch_bounds__(256) void relayout_kernel(
    const float* __restrict__ p4,   // [32][2048*36]
    float* __restrict__ at)         // [1152][2048]
{
    int i = blockIdx.x*256 + threadIdx.x;
    int f = i >> 11, r = i & 2047;
    int s = f >> 5,  c = f & 31;
    int t = r >> 5,  n = r & 31;
    int nt = n*64 + t;
    at[i] = p4[c*(BATCH*36) + nt*36 + s];
}

// ------ gate pre-projection -> gx2[st][wg][colX*32+n] (4KB/WG/step dense) ----
// global col oc = g*256 + wg*8 + u  ->  wg = (oc>>3)&31, colX = g*8+u
__global__ __launch_bounds__(256) void gx_gemm_kernel(
    const float* __restrict__ at,   // [1152][2048]
    const float* __restrict__ lw,   // [1408][1024] (rows 0..1151 = Wx)
    const float* __restrict__ lb,   // [1024]
    float* __restrict__ gx2)        // [64][32][1024]
{
    int lane = threadIdx.x & 63;
    int wv   = threadIdx.x >> 6;
    int r0   = blockIdx.x * 16;
    int oc   = blockIdx.y*256 + wv*64 + lane;
    float acc[16];
    float bias = lb[oc];
    #pragma unroll
    for(int i=0;i<16;i++) acc[i] = bias;
    #pragma unroll 4
    for(int k=0;k<1152;k++){
        float wval = lw[k*1024 + oc];
        const float* ap = at + k*2048 + r0;
        #pragma unroll
        for(int i=0;i<16;i++) acc[i] += ap[i] * wval;
    }
    int wg2  = (oc >> 3) & 31;
    int colX = ((oc >> 8) << 3) | (oc & 7);
    #pragma unroll
    for(int i=0;i<16;i++){
        int r = r0 + i, st2 = r >> 5, n = r & 31;
        gx2[(st2*32 + wg2)*1024 + colX*32 + n] = acc[i];
    }
}

// ---------------- LSTM: 32 persistent WGs, distributed flag sync -------------
// WG wg owns units wg*8..wg*8+8 (32 gate cols). Wh slice VGPR-resident.
// hbuf[par] is unit-major [256u][32n]: WG slice = 1KB contiguous publish.
// flags[wg*16]: # publishes by wg (init=1). Consumers poll 1 flag/lane.
__global__ __launch_bounds__(256) void lstm_kernel(
    const float* __restrict__ gx2,  // [64][32][1024], bias folded
    const float* __restrict__ lw,   // [1408][1024]
    const float* __restrict__ c0,   // [32][256]
    const float* __restrict__ h0,   // [32][256]
    float* __restrict__ feats,      // [2048][256], row = n*64+st
    float* __restrict__ hbuf,       // [2][8192] unit-major
    unsigned* __restrict__ flags)   // [32*16] zeroed
{
    __shared__ float h_s[32*260];        // [n][u], pad 260 (16B-aligned rows)
    __shared__ float part[4][32][33];
    __shared__ float gatef[1024];        // [colX*32+n]
    const int t    = threadIdx.x;
    const int wg   = blockIdx.x;
    const int col16= t & 15;
    const int kseg = t >> 4;
    const int lane = t & 63;
    const int wv   = t >> 6;
    const float* wh = lw + 1152*1024;

    const int gAc = ((col16>>3)<<8)      + wg*8 + (col16&7);
    const int gBc = (((col16+16)>>3)<<8) + wg*8 + ((col16+16)&7);
    float wAr[16], wBr[16];
    #pragma unroll
    for(int j=0;j<16;j++){
        wAr[j] = wh[(kseg*16+j)*1024 + gAc];
        wBr[j] = wh[(kseg*16+j)*1024 + gBc];
    }
    const int cn = t & 31, cu = t >> 5;
    const int uglob = wg*8 + cu;
    float c = c0[cn*256 + uglob];
    // initial publish: hbuf[0][wg*256+t] = h0 for (u=wg*8+(t>>5), n=t&31)
    {
        float hv = h0[(t&31)*256 + wg*8 + (t>>5)];
        __hip_atomic_store(&hbuf[wg*256 + t], hv, __ATOMIC_RELAXED,
                           __HIP_MEMORY_SCOPE_AGENT);
    }
    __syncthreads();   // drains vmcnt before flag
    if(t==0) __hip_atomic_store(&flags[wg*16], 1u, __ATOMIC_RELEASE,
                                __HIP_MEMORY_SCOPE_AGENT);

    for(int st=0; st<64; st++){
        // dense gx prefetch: one float4/thread, 4KB/WG contiguous
        float4 g4 = *(const float4*)(gx2 + (st*32 + wg)*1024 + t*4);
        // poll: lane L waits on producer L's flag (independent lines)
        if(lane < 32){
            unsigned want = (unsigned)(st + 1);
            while(__hip_atomic_load(&flags[lane*16], __ATOMIC_ACQUIRE,
                                    __HIP_MEMORY_SCOPE_AGENT) < want){}
        }
        // stage h: batch 16 ull loads into regs, then LDS-transpose
        {
            const unsigned long long* hsrc =
                (const unsigned long long*)(hbuf + (st&1)*8192);
            unsigned long long vbuf[16];
            #pragma unroll
            for(int r=0;r<16;r++)
                vbuf[r] = __hip_atomic_load(&hsrc[r*256 + t], __ATOMIC_RELAXED,
                                            __HIP_MEMORY_SCOPE_AGENT);
            #pragma unroll
            for(int r=0;r<16;r++){
                int u  = r*16 + (t>>4);
                int n0 = 2*(t & 15);
                union { unsigned long long q; float f[2]; } cv; cv.q = vbuf[r];
                h_s[n0*260 + u]     = cv.f[0];
                h_s[(n0+1)*260 + u] = cv.f[1];
            }
        }
        __syncthreads();
        // coalesced feats write for step st-1 (traj wg's full row, from LDS)
        if(st > 0)
            feats[(wg*64 + (st-1))*256 + t] = h_s[wg*260 + t];
        // dot phase
        #pragma unroll 4
        for(int n=0;n<32;n++){
            const float4* hp = (const float4*)&h_s[n*260 + kseg*16];
            float4 ha = hp[0], hb = hp[1], hc = hp[2], hd = hp[3];
            float pA = ha.x*wAr[0]  + ha.y*wAr[1]  + ha.z*wAr[2]  + ha.w*wAr[3]
                     + hb.x*wAr[4]  + hb.y*wAr[5]  + hb.z*wAr[6]  + hb.w*wAr[7]
                     + hc.x*wAr[8]  + hc.y*wAr[9]  + hc.z*wAr[10] + hc.w*wAr[11]
                     + hd.x*wAr[12] + hd.y*wAr[13] + hd.z*wAr[14] + hd.w*wAr[15];
            float pB = ha.x*wBr[0]  + ha.y*wBr[1]  + ha.z*wBr[2]  + ha.w*wBr[3]
                     + hb.x*wBr[4]  + hb.y*wBr[5]  + hb.z*wBr[6]  + hb.w*wBr[7]
                     + hc.x*wBr[8]  + hc.y*wBr[9]  + hc.z*wBr[10] + hc.w*wBr[11]
                     + hd.x*wBr[12] + hd.y*wBr[13] + hd.z*wBr[14] + hd.w*wBr[15];
            pA += __shfl_xor(pA, 16, 64);
            pA += __shfl_xor(pA, 32, 64);
            pB += __shfl_xor(pB, 16, 64);
            pB += __shfl_xor(pB, 32, 64);
            if(lane < 16){
                part[wv][n][lane]    = pA;
                part[wv][n][lane+16] = pB;
            }
        }
        __syncthreads();
        // assembly: thread t -> local idx t*4+e = colX*32+n
        {
            float ge[4] = {g4.x, g4.y, g4.z, g4.w};
            #pragma unroll
            for(int e=0;e<4;e++){
                int idx = t*4 + e;
                int colX = idx >> 5, nn = idx & 31;
                float s = part[0][nn][colX] + part[1][nn][colX]
                        + part[2][nn][colX] + part[3][nn][colX];
                gatef[idx] = s + ge[e];
            }
        }
        __syncthreads();
        // update: thread owns (traj cn, unit cu)
        float i_ = gatef[(cu     )*32 + cn];
        float j_ = gatef[(8  + cu)*32 + cn];
        float f_ = gatef[(16 + cu)*32 + cn];
        float o_ = gatef[(24 + cu)*32 + cn];
        c = c*sigmf(f_+1.f) + sigmf(i_)*tanhf(j_);
        float h = tanhf(c)*sigmf(o_);
        // publish: unit-major slot (wg*8+cu)*32+cn = wg*256+t  (coalesced)
        __hip_atomic_store(&hbuf[((st+1)&1)*8192 + wg*256 + t], h,
                           __ATOMIC_RELAXED, __HIP_MEMORY_SCOPE_AGENT);
        if(st == 63)
            feats[(cn*64 + 63)*256 + uglob] = h;   // once, scattered OK
        __syncthreads();   // drains vmcnt: all publishes complete
        if(t==0) __hip_atomic_store(&flags[wg*16], (unsigned)(st+2),
                                    __ATOMIC_RELEASE, __HIP_MEMORY_SCOPE_AGENT);
    }
}

// ---------------- final FC: logits[p][18] = feats[p] @ fc_w + fc_b ----------
__global__ __launch_bounds__(64) void fc_kernel(
    const float* __restrict__ feats, const float* __restrict__ fw,
    const float* __restrict__ fb,    float* __restrict__ out)
{
    __shared__ float h[256];
    int p = blockIdx.x, t = threadIdx.x;
    *(float4*)&h[t*4] = *(const float4*)(feats + p*256 + t*4);
    __syncthreads();
    if(t < 18){
        float acc = fb[t];
        for(int k=0;k<256;k++) acc += h[k]*fw[k*18 + t];
        out[p*18 + t] = acc;
    }
}

extern "C" void kernel_launch(void* const* d_in, const int* in_sizes, int n_in,
                              void* d_out, int out_size, void* d_ws, size_t ws_size,
                              hipStream_t stream) {
    const float* inp = (const float*)d_in[0];
    const float* w1  = (const float*)d_in[1];  const float* b1 = (const float*)d_in[2];
    const float* w2  = (const float*)d_in[3];  const float* b2 = (const float*)d_in[4];
    const float* w3  = (const float*)d_in[5];  const float* b3 = (const float*)d_in[6];
    const float* w4  = (const float*)d_in[7];  const float* b4 = (const float*)d_in[8];
    const float* lw  = (const float*)d_in[9];  const float* lb = (const float*)d_in[10];
    const float* fw  = (const float*)d_in[11]; const float* fb = (const float*)d_in[12];
    const float* c0  = (const float*)d_in[13]; const float* h0 = (const float*)d_in[14];
    float* out = (float*)d_out;
    float* ws  = (float*)d_ws;

    const size_t n1 = (size_t)32*3612672;   // conv1 out planes
    const size_t n3 = (size_t)32*247808;    // conv3 out planes
    const size_t n4 = (size_t)32*73728;     // conv4 out planes

    float* p1 = ws;
    float* p2 = p1 + n1;                    // conv2 out
    float* p3 = ws;                         // reuse p1 region (conv3 reads only p2)
    float* p4 = p3 + n3;
    float* at = p4 + n4;                    // [1152][2048]
    float* gx2   = at  + (size_t)1152*2048; // [64][32][1024]
    float* feats = gx2 + (size_t)2048*1024; // [2048][256]
    float* hbuf  = feats + (size_t)2048*256;// [2][8192]
    unsigned* flags = (unsigned*)(hbuf + 16384);  // [32*16]

    conv1_kernel<<<14112,256,0,stream>>>(inp, w1, b1, p1);
    convN_kernel<42,42,21,21,0><<<3528,256,0,stream>>>(p1, w2, b2, p2);
    convN_kernel<21,21,11,11,1><<<968,256,0,stream>>>(p2, w3, b3, p3);
    convN_kernel<11,11, 6, 6,1><<<288,256,0,stream>>>(p3, w4, b4, p4);
    relayout_kernel<<<9216,256,0,stream>>>(p4, at);
    gx_gemm_kernel<<<dim3(128,4),256,0,stream>>>(at, lw, lb, gx2);
    hipMemsetAsync(flags, 0, 32*16*sizeof(unsigned), stream);
    {
        void* args[] = { (void*)&gx2, (void*)&lw, (void*)&c0, (void*)&h0,
                         (void*)&feats, (void*)&hbuf, (void*)&flags };
        hipLaunchCooperativeKernel((void*)lstm_kernel, dim3(32), dim3(256),
                                   args, 0, stream);
    }
    fc_kernel<<<2048,64,0,stream>>>(feats, fw, fb, out);
}